// Round 1
// baseline (679.946 us; speedup 1.0000x reference)
//
#include <hip/hip_runtime.h>
#include <math.h>

#define LTOK 4096
#define EDIM 512
#define SDIM 1024
#define HDIM 150
#define MAXN 10
#define TOTAL_ROWS 40915   // sum_{n=1..10} (L - n + 1)

// ---------------------------------------------------------------------------
// Kernel 1: per-token work (one block per token l)
//   attns[l]  = scorer(states[l]; aW*)          (150-wide MLP, scalar out)
//   P1[l][:]  = states[l] @ sW1[0:1024, :]
//   P2[l][:]  = states[l] @ sW1[1024:2048, :]
//   PE[l][:]  = embeds[l] @ sW1[2048:2560, :]
// ---------------------------------------------------------------------------
__global__ __launch_bounds__(256) void token_kernel(
    const float* __restrict__ embeds, const float* __restrict__ states,
    const float* __restrict__ aW1, const float* __restrict__ ab1,
    const float* __restrict__ aW2, const float* __restrict__ ab2,
    const float* __restrict__ aW3, const float* __restrict__ ab3,
    const float* __restrict__ sW1,
    float* __restrict__ attns, float* __restrict__ P1,
    float* __restrict__ P2, float* __restrict__ PE)
{
    const int l = blockIdx.x;
    const int t = threadIdx.x;

    __shared__ float s[SDIM];
    __shared__ float e[EDIM];
    __shared__ float h1[HDIM];
    __shared__ float red[256];

    for (int k = t; k < SDIM; k += 256) s[k] = states[l * SDIM + k];
    for (int k = t; k < EDIM; k += 256) e[k] = embeds[l * EDIM + k];
    __syncthreads();

    // attention scorer: layer 1 (S -> H) + relu
    if (t < HDIM) {
        float a1 = ab1[t];
        for (int k = 0; k < SDIM; ++k) a1 += s[k] * aW1[k * HDIM + t];
        h1[t] = fmaxf(a1, 0.f);
    }
    __syncthreads();

    // layer 2 (H -> H) + relu, fused with layer 3 weight
    float v = 0.f;
    if (t < HDIM) {
        float a2 = ab2[t];
        for (int k = 0; k < HDIM; ++k) a2 += h1[k] * aW2[k * HDIM + t];
        v = fmaxf(a2, 0.f) * aW3[t];
    }
    red[t] = v;
    __syncthreads();
    for (int sd = 128; sd > 0; sd >>= 1) {
        if (t < sd) red[t] += red[t + sd];
        __syncthreads();
    }
    if (t == 0) attns[l] = red[0] + ab3[0];

    // sm-scorer first-layer projections (no bias here; sb1 added in span kernel)
    if (t < HDIM) {
        float p1 = 0.f, p2 = 0.f, pe = 0.f;
        for (int k = 0; k < SDIM; ++k) p1 += s[k] * sW1[k * HDIM + t];
        for (int k = 0; k < SDIM; ++k) p2 += s[k] * sW1[(SDIM + k) * HDIM + t];
        for (int k = 0; k < EDIM; ++k) pe += e[k] * sW1[(2 * SDIM + k) * HDIM + t];
        P1[l * HDIM + t] = p1;
        P2[l * HDIM + t] = p2;
        PE[l * HDIM + t] = pe;
    }
}

// ---------------------------------------------------------------------------
// Kernel 2: one block per output row (n, m)
//   w      = softmax(attns[m : m+n])
//   h1     = relu(P1[m] + P2[m+n-1] + sum_j w[j]*PE[m+j] + sb1)
//   h2     = relu(h1 @ sW2 + sb2)
//   out    = h2 @ sW3 + sb3
// ---------------------------------------------------------------------------
__global__ __launch_bounds__(256) void span_kernel(
    const float* __restrict__ attns, const float* __restrict__ P1,
    const float* __restrict__ P2, const float* __restrict__ PE,
    const float* __restrict__ sb1, const float* __restrict__ sW2,
    const float* __restrict__ sb2, const float* __restrict__ sW3,
    const float* __restrict__ sb3, float* __restrict__ out)
{
    const int row = blockIdx.x;
    const int t = threadIdx.x;

    // decode row -> (n, m): rows are concatenated per n = 1..10, M = L-n+1 each
    int idx = row;
    int n = 1, m = 0;
    for (int nn = 1; nn <= MAXN; ++nn) {
        const int M = LTOK - nn + 1;
        if (idx < M) { n = nn; m = idx; break; }
        idx -= M;
    }

    __shared__ float w[MAXN];
    __shared__ float h1[HDIM];
    __shared__ float red[256];

    if (t == 0) {
        float mx = -1e30f;
        for (int j = 0; j < n; ++j) mx = fmaxf(mx, attns[m + j]);
        float tmp[MAXN];
        float sum = 0.f;
        for (int j = 0; j < n; ++j) { tmp[j] = expf(attns[m + j] - mx); sum += tmp[j]; }
        const float inv = 1.f / sum;
        for (int j = 0; j < n; ++j) w[j] = tmp[j] * inv;
    }
    __syncthreads();

    if (t < HDIM) {
        float acc = P1[m * HDIM + t] + P2[(m + n - 1) * HDIM + t] + sb1[t];
        for (int j = 0; j < n; ++j) acc += w[j] * PE[(m + j) * HDIM + t];
        h1[t] = fmaxf(acc, 0.f);
    }
    __syncthreads();

    float v = 0.f;
    if (t < HDIM) {
        float acc = sb2[t];
        for (int k = 0; k < HDIM; ++k) acc += h1[k] * sW2[k * HDIM + t];
        v = fmaxf(acc, 0.f) * sW3[t];
    }
    red[t] = v;
    __syncthreads();
    for (int sd = 128; sd > 0; sd >>= 1) {
        if (t < sd) red[t] += red[t + sd];
        __syncthreads();
    }
    if (t == 0) out[row] = red[0] + sb3[0];
}

// ---------------------------------------------------------------------------
extern "C" void kernel_launch(void* const* d_in, const int* in_sizes, int n_in,
                              void* d_out, int out_size, void* d_ws, size_t ws_size,
                              hipStream_t stream) {
    const float* embeds = (const float*)d_in[0];
    const float* states = (const float*)d_in[1];
    const float* aW1 = (const float*)d_in[2];
    const float* ab1 = (const float*)d_in[3];
    const float* aW2 = (const float*)d_in[4];
    const float* ab2 = (const float*)d_in[5];
    const float* aW3 = (const float*)d_in[6];
    const float* ab3 = (const float*)d_in[7];
    const float* sW1 = (const float*)d_in[8];
    const float* sb1 = (const float*)d_in[9];
    const float* sW2 = (const float*)d_in[10];
    const float* sb2 = (const float*)d_in[11];
    const float* sW3 = (const float*)d_in[12];
    const float* sb3 = (const float*)d_in[13];
    float* out = (float*)d_out;

    // workspace layout (floats): attns[4096] | P1[4096*150] | P2 | PE  ~= 7.4 MB
    float* ws    = (float*)d_ws;
    float* attns = ws;
    float* P1    = attns + LTOK;
    float* P2    = P1 + LTOK * HDIM;
    float* PE    = P2 + LTOK * HDIM;

    token_kernel<<<LTOK, 256, 0, stream>>>(embeds, states, aW1, ab1, aW2, ab2,
                                           aW3, ab3, sW1, attns, P1, P2, PE);
    span_kernel<<<TOTAL_ROWS, 256, 0, stream>>>(attns, P1, P2, PE, sb1, sW2,
                                                sb2, sW3, sb3, out);
}

// Round 2
// 369.552 us; speedup vs baseline: 1.8399x; 1.8399x over previous
//
#include <hip/hip_runtime.h>
#include <math.h>

#define LTOK 4096
#define EDIM 512
#define SDIM 1024
#define HDIM 150
#define MAXN 10
#define TOTAL_ROWS 40915   // sum_{n=1..10} (L - n + 1)
#define TB 16              // tokens per block (kernel A)
#define RB 24              // rows per block  (kernel B)

// ---------------------------------------------------------------------------
// Kernel A: fused per-token work, 16 tokens/block, 640 threads.
// Thread t owns one output column:
//   t in [0,150):    P1 col t        = states @ sW1[0:1024]       (K=1024)
//   t in [150,300):  P2 col t-150    = states @ sW1[1024:2048]    (K=1024)
//   t in [300,450):  attn-h1 col     = states @ aW1               (K=1024)
//   t in [450,600):  PE col t-450    = embeds @ sW1[2048:2560]    (K=512)
// 16 accumulators/thread -> each weight load feeds 16 FMAs.
// Epilogue: attn layers 2+3 -> attns[16].
// ---------------------------------------------------------------------------
__global__ __launch_bounds__(640) void token_fused(
    const float* __restrict__ embeds, const float* __restrict__ states,
    const float* __restrict__ aW1, const float* __restrict__ ab1,
    const float* __restrict__ aW2, const float* __restrict__ ab2,
    const float* __restrict__ aW3, const float* __restrict__ ab3,
    const float* __restrict__ sW1,
    float* __restrict__ attns, float* __restrict__ P1,
    float* __restrict__ P2, float* __restrict__ PE)
{
    const int tok0 = blockIdx.x * TB;
    const int tid  = threadIdx.x;

    __shared__ __align__(16) float s_tile[TB][128];
    __shared__ __align__(16) float e_tile[TB][128];
    __shared__ float ah1[TB][152];
    __shared__ float red2[TB][152];

    // per-thread column setup
    const float* wbase = nullptr;
    int kmax = 0;
    bool use_e = false;
    if (tid < 150)      { wbase = sW1 + tid;                          kmax = 1024; }
    else if (tid < 300) { wbase = sW1 + 1024 * HDIM + (tid - 150);    kmax = 1024; }
    else if (tid < 450) { wbase = aW1 + (tid - 300);                  kmax = 1024; }
    else if (tid < 600) { wbase = sW1 + 2048 * HDIM + (tid - 450);    kmax = 512; use_e = true; }

    float acc[TB];
#pragma unroll
    for (int i = 0; i < TB; ++i) acc[i] = 0.f;

    for (int kk = 0; kk < SDIM; kk += 128) {
        __syncthreads();   // previous tile fully consumed before overwrite
        // stage states tile: 16 tokens x 128 floats = 512 float4
        for (int idx = tid; idx < TB * 32; idx += 640) {
            const int tok = idx >> 5, q = idx & 31;
            *(float4*)&s_tile[tok][q * 4] =
                *(const float4*)&states[(tok0 + tok) * SDIM + kk + q * 4];
        }
        if (kk < EDIM) {
            for (int idx = tid; idx < TB * 32; idx += 640) {
                const int tok = idx >> 5, q = idx & 31;
                *(float4*)&e_tile[tok][q * 4] =
                    *(const float4*)&embeds[(tok0 + tok) * EDIM + kk + q * 4];
            }
        }
        __syncthreads();

        if (wbase != nullptr && kk < kmax) {
            const float (*inp)[128] = use_e ? e_tile : s_tile;
            const float* wp = wbase + (size_t)kk * HDIM;
            for (int k4 = 0; k4 < 128; k4 += 4) {
                const float w0 = wp[(k4 + 0) * HDIM];
                const float w1 = wp[(k4 + 1) * HDIM];
                const float w2 = wp[(k4 + 2) * HDIM];
                const float w3 = wp[(k4 + 3) * HDIM];
#pragma unroll
                for (int t = 0; t < TB; ++t) {
                    const float4 sv = *(const float4*)&inp[t][k4];
                    float a = acc[t];
                    a = fmaf(sv.x, w0, a);
                    a = fmaf(sv.y, w1, a);
                    a = fmaf(sv.z, w2, a);
                    a = fmaf(sv.w, w3, a);
                    acc[t] = a;
                }
            }
        }
    }

    // store projections / stage attn-h1
    if (tid < 150) {
#pragma unroll
        for (int t = 0; t < TB; ++t) P1[(tok0 + t) * HDIM + tid] = acc[t];
    } else if (tid < 300) {
        const int c = tid - 150;
#pragma unroll
        for (int t = 0; t < TB; ++t) P2[(tok0 + t) * HDIM + c] = acc[t];
    } else if (tid < 450) {
        const int c = tid - 300;
        const float b = ab1[c];
#pragma unroll
        for (int t = 0; t < TB; ++t) ah1[t][c] = fmaxf(acc[t] + b, 0.f);
    } else if (tid < 600) {
        const int c = tid - 450;
#pragma unroll
        for (int t = 0; t < TB; ++t) PE[(tok0 + t) * HDIM + c] = acc[t];
    }
    __syncthreads();

    // attn layer 2 (+ fused layer-3 weight): items (tok, col)
    for (int item = tid; item < TB * HDIM; item += 640) {
        const int t = item / HDIM, c = item % HDIM;
        float a = ab2[c];
        for (int k = 0; k < HDIM; ++k) a = fmaf(ah1[t][k], aW2[k * HDIM + c], a);
        red2[t][c] = fmaxf(a, 0.f) * aW3[c];
    }
    __syncthreads();
    if (tid < TB) {
        float ssum = 0.f;
        for (int c = 0; c < HDIM; ++c) ssum += red2[tid][c];
        attns[tok0 + tid] = ssum + ab3[0];
    }
}

// ---------------------------------------------------------------------------
// Kernel B: 24 rows/block, 256 threads.
//   phase 1: softmax weights (threads 0..23, one row each)
//   phase 2: h1[r][c] = relu(P1[m] + P2[m+n-1] + sum_j w_j PE[m+j] + sb1)
//   phase 3: register-tiled 24x150 @ 150x150 with sW2 in LDS K-tiles;
//            thread item (rq,cq) owns rows 4rq..+3 x cols 4cq..+3 (16 acc).
//   epilogue: relu(+sb2) * sW3, per-row reduce, +sb3.
// ---------------------------------------------------------------------------
__global__ __launch_bounds__(256) void span_kernel(
    const float* __restrict__ attns, const float* __restrict__ P1,
    const float* __restrict__ P2, const float* __restrict__ PE,
    const float* __restrict__ sb1, const float* __restrict__ sW2,
    const float* __restrict__ sb2, const float* __restrict__ sW3,
    const float* __restrict__ sb3, float* __restrict__ out)
{
    const int row0 = blockIdx.x * RB;
    const int tid  = threadIdx.x;

    __shared__ float w[RB][MAXN];
    __shared__ int   sm[RB], sn[RB];
    __shared__ float h1[RB][152];
    __shared__ __align__(16) float Wt[50][152];
    __shared__ float red[RB][40];

    if (tid < RB) {
        int row = row0 + tid;
        if (row >= TOTAL_ROWS) row = TOTAL_ROWS - 1;   // clamp; store guarded later
        int idx = row, n = 1, m = 0;
        for (int nn = 1; nn <= MAXN; ++nn) {
            const int M = LTOK - nn + 1;
            if (idx < M) { n = nn; m = idx; break; }
            idx -= M;
        }
        sm[tid] = m; sn[tid] = n;
        float mx = -1e30f;
        for (int j = 0; j < n; ++j) mx = fmaxf(mx, attns[m + j]);
        float tmp[MAXN]; float sum = 0.f;
        for (int j = 0; j < n; ++j) { tmp[j] = expf(attns[m + j] - mx); sum += tmp[j]; }
        const float inv = 1.f / sum;
        for (int j = 0; j < n; ++j) w[tid][j] = tmp[j] * inv;
    }
    __syncthreads();

    // phase 2: h1
    for (int item = tid; item < RB * HDIM; item += 256) {
        const int r = item / HDIM, c = item % HDIM;
        const int m = sm[r], n = sn[r];
        float a = P1[m * HDIM + c] + P2[(m + n - 1) * HDIM + c] + sb1[c];
        for (int j = 0; j < n; ++j) a = fmaf(w[r][j], PE[(m + j) * HDIM + c], a);
        h1[r][c] = fmaxf(a, 0.f);
    }

    // phase 3: layer-2 GEMM, K tiled by 50
    float acc[4][4];
#pragma unroll
    for (int i = 0; i < 4; ++i)
#pragma unroll
        for (int j = 0; j < 4; ++j) acc[i][j] = 0.f;

    const int rq = tid / 38, cq = tid % 38;   // 6 x 38 = 228 active threads
    const bool active = tid < 228;

    for (int kt = 0; kt < 3; ++kt) {
        __syncthreads();   // h1 ready (kt=0) / previous Wt consumed
        for (int idx = tid; idx < 50 * 152; idx += 256) {
            const int k = idx / 152, c = idx % 152;
            Wt[k][c] = (c < HDIM) ? sW2[(kt * 50 + k) * HDIM + c] : 0.f;
        }
        __syncthreads();
        if (active) {
            for (int k = 0; k < 50; ++k) {
                const int kg = kt * 50 + k;
                const float4 wq = *(const float4*)&Wt[k][cq * 4];
                const float h0 = h1[rq * 4 + 0][kg];
                const float h1v = h1[rq * 4 + 1][kg];
                const float h2v = h1[rq * 4 + 2][kg];
                const float h3v = h1[rq * 4 + 3][kg];
                acc[0][0] = fmaf(h0, wq.x, acc[0][0]);
                acc[0][1] = fmaf(h0, wq.y, acc[0][1]);
                acc[0][2] = fmaf(h0, wq.z, acc[0][2]);
                acc[0][3] = fmaf(h0, wq.w, acc[0][3]);
                acc[1][0] = fmaf(h1v, wq.x, acc[1][0]);
                acc[1][1] = fmaf(h1v, wq.y, acc[1][1]);
                acc[1][2] = fmaf(h1v, wq.z, acc[1][2]);
                acc[1][3] = fmaf(h1v, wq.w, acc[1][3]);
                acc[2][0] = fmaf(h2v, wq.x, acc[2][0]);
                acc[2][1] = fmaf(h2v, wq.y, acc[2][1]);
                acc[2][2] = fmaf(h2v, wq.z, acc[2][2]);
                acc[2][3] = fmaf(h2v, wq.w, acc[2][3]);
                acc[3][0] = fmaf(h3v, wq.x, acc[3][0]);
                acc[3][1] = fmaf(h3v, wq.y, acc[3][1]);
                acc[3][2] = fmaf(h3v, wq.z, acc[3][2]);
                acc[3][3] = fmaf(h3v, wq.w, acc[3][3]);
            }
        }
    }

    // epilogue: relu(+sb2)*sW3, partial row sums
    if (active) {
#pragma unroll
        for (int i = 0; i < 4; ++i) {
            float p = 0.f;
#pragma unroll
            for (int j = 0; j < 4; ++j) {
                const int c = cq * 4 + j;
                if (c < HDIM)
                    p += fmaxf(acc[i][j] + sb2[c], 0.f) * sW3[c];
            }
            red[rq * 4 + i][cq] = p;
        }
    }
    __syncthreads();
    if (tid < RB) {
        const int row = row0 + tid;
        if (row < TOTAL_ROWS) {
            float ssum = 0.f;
            for (int q = 0; q < 38; ++q) ssum += red[tid][q];
            out[row] = ssum + sb3[0];
        }
    }
}

// ---------------------------------------------------------------------------
extern "C" void kernel_launch(void* const* d_in, const int* in_sizes, int n_in,
                              void* d_out, int out_size, void* d_ws, size_t ws_size,
                              hipStream_t stream) {
    const float* embeds = (const float*)d_in[0];
    const float* states = (const float*)d_in[1];
    const float* aW1 = (const float*)d_in[2];
    const float* ab1 = (const float*)d_in[3];
    const float* aW2 = (const float*)d_in[4];
    const float* ab2 = (const float*)d_in[5];
    const float* aW3 = (const float*)d_in[6];
    const float* ab3 = (const float*)d_in[7];
    const float* sW1 = (const float*)d_in[8];
    const float* sb1 = (const float*)d_in[9];
    const float* sW2 = (const float*)d_in[10];
    const float* sb2 = (const float*)d_in[11];
    const float* sW3 = (const float*)d_in[12];
    const float* sb3 = (const float*)d_in[13];
    float* out = (float*)d_out;

    // workspace: attns[4096] | P1 | P2 | PE (4096*150 each) ~= 7.4 MB
    float* ws    = (float*)d_ws;
    float* attns = ws;
    float* P1    = attns + LTOK;
    float* P2    = P1 + LTOK * HDIM;
    float* PE    = P2 + LTOK * HDIM;

    token_fused<<<LTOK / TB, 640, 0, stream>>>(embeds, states, aW1, ab1, aW2, ab2,
                                               aW3, ab3, sW1, attns, P1, P2, PE);
    span_kernel<<<(TOTAL_ROWS + RB - 1) / RB, 256, 0, stream>>>(
        attns, P1, P2, PE, sb1, sW2, sb2, sW3, sb3, out);
}

// Round 4
// 268.306 us; speedup vs baseline: 2.5342x; 1.3774x over previous
//
#include <hip/hip_runtime.h>
#include <hip/hip_bf16.h>
#include <math.h>

#define LTOK 4096
#define EDIM 512
#define SDIM 1024
#define HDIM 150
#define MAXN 10
#define TOTAL_ROWS 40915   // sum_{n=1..10} (L - n + 1)
#define KA 1536            // padded K for token GEMM: 1024 states + 512 embeds
#define NC 640             // padded col count (600 real: P1|P2|AH1|PE)
#define K2 160             // padded K and N for span layer-2 (150 real)

typedef __attribute__((ext_vector_type(8))) short bfrag;   // 8 bf16 in 4 VGPRs
typedef __attribute__((ext_vector_type(4))) float ffrag;   // MFMA C/D

__device__ inline ushort f2bf(float f) {
    __hip_bfloat16 h = __float2bfloat16(f);
    return *(ushort*)&h;
}
__device__ inline float bf2f(ushort u) {
    __hip_bfloat16 h = *(__hip_bfloat16*)&u;
    return __bfloat162float(h);
}

#define ITEMS_A  (LTOK * (KA / 8))   // 786432
#define ITEMS_W  (NC * (KA / 8))     // 122880
#define ITEMS_W2 (K2 * (K2 / 8))     // 3200
#define ITEMS_TOT (ITEMS_A + ITEMS_W + ITEMS_W2)

// ---------------------------------------------------------------------------
// prep: fp32 -> bf16 conversions.
//   Ab[tok][KA]   = [states | embeds] (bf16)
//   Wh/Wl[c][KA]  = transposed, zero-padded layer-1 weights, hi/lo split
//     k in [0,1024)  : states-region weights (P1 / P2 / attn groups)
//     k in [1024,1536): embeds-region weights (PE group)    <-- fixed placement
//   W2h/W2l[c][K2]= transposed, zero-padded sW2, hi/lo split
// ---------------------------------------------------------------------------
__global__ __launch_bounds__(256) void prep_kernel(
    const float* __restrict__ embeds, const float* __restrict__ states,
    const float* __restrict__ aW1, const float* __restrict__ sW1,
    const float* __restrict__ sW2,
    ushort* __restrict__ Ab, ushort* __restrict__ Wh, ushort* __restrict__ Wl,
    ushort* __restrict__ W2h, ushort* __restrict__ W2l)
{
    int it = blockIdx.x * 256 + threadIdx.x;
    if (it < ITEMS_A) {
        const int r = it / (KA / 8), kc = it % (KA / 8);
        const int k0 = kc * 8;
        const float* src = (k0 < SDIM) ? (states + (size_t)r * SDIM + k0)
                                       : (embeds + (size_t)r * EDIM + (k0 - SDIM));
        const float4 v0 = *(const float4*)src;
        const float4 v1 = *(const float4*)(src + 4);
        ushort o[8] = {f2bf(v0.x), f2bf(v0.y), f2bf(v0.z), f2bf(v0.w),
                       f2bf(v1.x), f2bf(v1.y), f2bf(v1.z), f2bf(v1.w)};
        *(uint4*)(Ab + (size_t)r * KA + k0) = *(uint4*)o;
        return;
    }
    it -= ITEMS_A;
    if (it < ITEMS_W) {
        const int c = it / (KA / 8), kc = it % (KA / 8);
        const int k0 = kc * 8;
        const int g = (c < 600) ? (c / HDIM) : -1;
        const int cj = c % HDIM;
        ushort oh[8], ol[8];
        for (int j = 0; j < 8; ++j) {
            const int k = k0 + j;
            float wv = 0.f;
            if (g == 0 && k < SDIM) wv = sW1[(size_t)k * HDIM + cj];
            else if (g == 1 && k < SDIM) wv = sW1[(size_t)(SDIM + k) * HDIM + cj];
            else if (g == 2 && k < SDIM) wv = aW1[(size_t)k * HDIM + cj];
            else if (g == 3 && k >= SDIM) wv = sW1[(size_t)(SDIM + k) * HDIM + cj]; // rows 2048+(k-1024)
            const ushort hb = f2bf(wv);
            oh[j] = hb;
            ol[j] = f2bf(wv - bf2f(hb));
        }
        *(uint4*)(Wh + (size_t)c * KA + k0) = *(uint4*)oh;
        *(uint4*)(Wl + (size_t)c * KA + k0) = *(uint4*)ol;
        return;
    }
    it -= ITEMS_W;
    if (it < ITEMS_W2) {
        const int c = it / (K2 / 8), kc = it % (K2 / 8);
        const int k0 = kc * 8;
        ushort oh[8], ol[8];
        for (int j = 0; j < 8; ++j) {
            const int k = k0 + j;
            float wv = (c < HDIM && k < HDIM) ? sW2[(size_t)k * HDIM + c] : 0.f;
            const ushort hb = f2bf(wv);
            oh[j] = hb;
            ol[j] = f2bf(wv - bf2f(hb));
        }
        *(uint4*)(W2h + (size_t)c * K2 + k0) = *(uint4*)oh;
        *(uint4*)(W2l + (size_t)c * K2 + k0) = *(uint4*)ol;
    }
}

// ---------------------------------------------------------------------------
// k_proj: C[4096 x 640] = Ab[4096 x 1536] @ W  via mfma_f32_16x16x32_bf16.
// BM=128, BN=64; 4 waves as 2x2, wave tile 64x32 (4x2 MFMA tiles).
// A staged in LDS; W hi/lo frags streamed from L2-resident global.
// Epilogue routes cols: [0,150)->P1, [150,300)->P2, [300,450)->relu(+ab1)->AH1,
// [450,600)->PE.
// ---------------------------------------------------------------------------
#define BM 128
#define BN 64
__global__ __launch_bounds__(256) void k_proj(
    const ushort* __restrict__ Ab, const ushort* __restrict__ Wh,
    const ushort* __restrict__ Wl, const float* __restrict__ ab1,
    float* __restrict__ P1, float* __restrict__ P2,
    float* __restrict__ PE, float* __restrict__ AH1)
{
    const int bN = blockIdx.x / 32, bM = blockIdx.x % 32;
    const int tid = threadIdx.x;
    const int w = tid >> 6, lane = tid & 63;
    const int quad = lane >> 4, l16 = lane & 15;
    const int wm = w & 1, wn = w >> 1;

    __shared__ __align__(16) ushort A_lds[BM * 32];

    ffrag acc[4][2];
#pragma unroll
    for (int t = 0; t < 4; ++t)
#pragma unroll
        for (int u = 0; u < 2; ++u) acc[t][u] = (ffrag){0.f, 0.f, 0.f, 0.f};

    const int rowg0 = bM * BM;
    const int srow = tid >> 2, skc = tid & 3;   // staging: 64 rows x 4 k-chunks

    for (int kt = 0; kt < KA / 32; ++kt) {
        const int k0 = kt * 32;
        const uint4 sv0 = *(const uint4*)(Ab + (size_t)(rowg0 + srow) * KA + k0 + skc * 8);
        const uint4 sv1 = *(const uint4*)(Ab + (size_t)(rowg0 + 64 + srow) * KA + k0 + skc * 8);
        __syncthreads();
        *(uint4*)&A_lds[srow * 32 + skc * 8] = sv0;
        *(uint4*)&A_lds[(64 + srow) * 32 + skc * 8] = sv1;
        __syncthreads();

        bfrag af[4];
#pragma unroll
        for (int t = 0; t < 4; ++t)
            af[t] = *(const bfrag*)&A_lds[(wm * 64 + t * 16 + l16) * 32 + quad * 8];

#pragma unroll
        for (int u = 0; u < 2; ++u) {
            const int col = bN * BN + wn * 32 + u * 16 + l16;
            const bfrag bh = *(const bfrag*)(Wh + (size_t)col * KA + k0 + quad * 8);
            const bfrag bl = *(const bfrag*)(Wl + (size_t)col * KA + k0 + quad * 8);
#pragma unroll
            for (int t = 0; t < 4; ++t) {
                acc[t][u] = __builtin_amdgcn_mfma_f32_16x16x32_bf16(af[t], bh, acc[t][u], 0, 0, 0);
                acc[t][u] = __builtin_amdgcn_mfma_f32_16x16x32_bf16(af[t], bl, acc[t][u], 0, 0, 0);
            }
        }
    }

#pragma unroll
    for (int t = 0; t < 4; ++t)
#pragma unroll
        for (int u = 0; u < 2; ++u) {
            const int col = bN * BN + wn * 32 + u * 16 + l16;
#pragma unroll
            for (int r = 0; r < 4; ++r) {
                const int row = bM * BM + wm * 64 + t * 16 + quad * 4 + r;
                const float v = acc[t][u][r];
                if (col < 150)      P1[(size_t)row * HDIM + col] = v;
                else if (col < 300) P2[(size_t)row * HDIM + (col - 150)] = v;
                else if (col < 450) AH1[(size_t)row * HDIM + (col - 300)] =
                                        fmaxf(v + ab1[col - 300], 0.f);
                else if (col < 600) PE[(size_t)row * HDIM + (col - 450)] = v;
            }
        }
}

// ---------------------------------------------------------------------------
// attn_tail: attns[tok] = (relu(AH1 @ aW2 + ab2) @ aW3 + ab3), 16 tok/block.
// ---------------------------------------------------------------------------
__global__ __launch_bounds__(256) void attn_tail(
    const float* __restrict__ AH1, const float* __restrict__ aW2,
    const float* __restrict__ ab2, const float* __restrict__ aW3,
    const float* __restrict__ ab3, float* __restrict__ attns)
{
    const int tok0 = blockIdx.x * 16;
    const int tid = threadIdx.x;
    __shared__ float ah[16][152];
    __shared__ float red[16][152];
    for (int i = tid; i < 16 * HDIM; i += 256) {
        const int t = i / HDIM, c = i % HDIM;
        ah[t][c] = AH1[(size_t)(tok0 + t) * HDIM + c];
    }
    __syncthreads();
    for (int i = tid; i < 16 * HDIM; i += 256) {
        const int t = i / HDIM, c = i % HDIM;
        float a = ab2[c];
        for (int k = 0; k < HDIM; ++k) a = fmaf(ah[t][k], aW2[k * HDIM + c], a);
        red[t][c] = fmaxf(a, 0.f) * aW3[c];
    }
    __syncthreads();
    if (tid < 16) {
        float s = 0.f;
        for (int c = 0; c < HDIM; ++c) s += red[tid][c];
        attns[tok0 + tid] = s + ab3[0];
    }
}

// ---------------------------------------------------------------------------
// span: 64 rows/block. softmax -> h1 (fp32, ->bf16 LDS) -> MFMA layer-2
// (A-frags cached in regs: 5 LDS reads/wave total; W2 hi/lo from global)
// -> relu/sW3 epilogue -> shfl reduce -> out.
// ---------------------------------------------------------------------------
#define RB2 64
__global__ __launch_bounds__(256) void span_kernel(
    const float* __restrict__ attns, const float* __restrict__ P1,
    const float* __restrict__ P2, const float* __restrict__ PE,
    const float* __restrict__ sb1, const ushort* __restrict__ W2h,
    const ushort* __restrict__ W2l, const float* __restrict__ sb2,
    const float* __restrict__ sW3, const float* __restrict__ sb3,
    float* __restrict__ out)
{
    const int row0 = blockIdx.x * RB2;
    const int tid = threadIdx.x;
    const int w = tid >> 6, lane = tid & 63, quad = lane >> 4, l16 = lane & 15;

    __shared__ __align__(16) ushort h1b[RB2 * K2];
    __shared__ float wgt[RB2][MAXN];
    __shared__ int sm[RB2], sn[RB2];

    if (tid < RB2) {
        int row = row0 + tid;
        if (row >= TOTAL_ROWS) row = TOTAL_ROWS - 1;
        int idx = row, n = 1, m = 0;
        for (int nn = 1; nn <= MAXN; ++nn) {
            const int M = LTOK - nn + 1;
            if (idx < M) { n = nn; m = idx; break; }
            idx -= M;
        }
        sm[tid] = m; sn[tid] = n;
        float mx = -1e30f;
        for (int j = 0; j < n; ++j) mx = fmaxf(mx, attns[m + j]);
        float tp[MAXN]; float s = 0.f;
        for (int j = 0; j < n; ++j) { tp[j] = expf(attns[m + j] - mx); s += tp[j]; }
        const float inv = 1.f / s;
        for (int j = 0; j < n; ++j) wgt[tid][j] = tp[j] * inv;
    }
    __syncthreads();

    // phase 1: h1 fp32 -> bf16 LDS (2 cols per item), k-pad zeroed
    for (int item = tid; item < RB2 * (K2 / 2); item += 256) {
        const int r = item / (K2 / 2), cp = item % (K2 / 2);
        const int c0 = cp * 2, c1 = c0 + 1;
        const int m = sm[r], n = sn[r];
        float v0 = 0.f, v1 = 0.f;
        if (c0 < HDIM) {
            v0 = P1[(size_t)m * HDIM + c0] + P2[(size_t)(m + n - 1) * HDIM + c0] + sb1[c0];
            for (int j = 0; j < n; ++j) v0 = fmaf(wgt[r][j], PE[(size_t)(m + j) * HDIM + c0], v0);
            v0 = fmaxf(v0, 0.f);
        }
        if (c1 < HDIM) {
            v1 = P1[(size_t)m * HDIM + c1] + P2[(size_t)(m + n - 1) * HDIM + c1] + sb1[c1];
            for (int j = 0; j < n; ++j) v1 = fmaf(wgt[r][j], PE[(size_t)(m + j) * HDIM + c1], v1);
            v1 = fmaxf(v1, 0.f);
        }
        const uint pk = (uint)f2bf(v0) | ((uint)f2bf(v1) << 16);
        ((uint*)h1b)[(r * K2 + c0) >> 1] = pk;
    }
    __syncthreads();

    // phase 2: wave w handles rows w*16..w*16+15 across all 10 col-tiles
    bfrag af[5];
#pragma unroll
    for (int ks = 0; ks < 5; ++ks)
        af[ks] = *(const bfrag*)&h1b[(w * 16 + l16) * K2 + ks * 32 + quad * 8];

    float part[4] = {0.f, 0.f, 0.f, 0.f};
    for (int ct = 0; ct < 10; ++ct) {
        ffrag acc = (ffrag){0.f, 0.f, 0.f, 0.f};
        const int col = ct * 16 + l16;
        const ushort* bh = W2h + (size_t)col * K2;
        const ushort* bl = W2l + (size_t)col * K2;
#pragma unroll
        for (int ks = 0; ks < 5; ++ks) {
            const bfrag fh = *(const bfrag*)(bh + ks * 32 + quad * 8);
            const bfrag fl = *(const bfrag*)(bl + ks * 32 + quad * 8);
            acc = __builtin_amdgcn_mfma_f32_16x16x32_bf16(af[ks], fh, acc, 0, 0, 0);
            acc = __builtin_amdgcn_mfma_f32_16x16x32_bf16(af[ks], fl, acc, 0, 0, 0);
        }
        const float s2 = (col < HDIM) ? sb2[col] : 0.f;
        const float s3 = (col < HDIM) ? sW3[col] : 0.f;
#pragma unroll
        for (int r = 0; r < 4; ++r) part[r] += fmaxf(acc[r] + s2, 0.f) * s3;
    }

    // reduce over the 16 lanes (l16) of each row group
#pragma unroll
    for (int off = 1; off < 16; off <<= 1) {
#pragma unroll
        for (int r = 0; r < 4; ++r) part[r] += __shfl_xor(part[r], off, 64);
    }
    if (l16 == 0) {
        const float b3 = sb3[0];
#pragma unroll
        for (int r = 0; r < 4; ++r) {
            const int row = row0 + w * 16 + quad * 4 + r;
            if (row < TOTAL_ROWS) out[row] = part[r] + b3;
        }
    }
}

// ---------------------------------------------------------------------------
extern "C" void kernel_launch(void* const* d_in, const int* in_sizes, int n_in,
                              void* d_out, int out_size, void* d_ws, size_t ws_size,
                              hipStream_t stream) {
    const float* embeds = (const float*)d_in[0];
    const float* states = (const float*)d_in[1];
    const float* aW1 = (const float*)d_in[2];
    const float* ab1 = (const float*)d_in[3];
    const float* aW2 = (const float*)d_in[4];
    const float* ab2 = (const float*)d_in[5];
    const float* aW3 = (const float*)d_in[6];
    const float* ab3 = (const float*)d_in[7];
    const float* sW1 = (const float*)d_in[8];
    const float* sb1 = (const float*)d_in[9];
    const float* sW2 = (const float*)d_in[10];
    const float* sb2 = (const float*)d_in[11];
    const float* sW3 = (const float*)d_in[12];
    const float* sb3 = (const float*)d_in[13];
    float* out = (float*)d_out;

    // ws layout: fp32 attns | P1 | P2 | PE | AH1, then bf16 Ab | Wh | Wl | W2h | W2l
    float* attns = (float*)d_ws;                       // 4096
    float* P1 = attns + LTOK;                          // 4096*150
    float* P2 = P1 + (size_t)LTOK * HDIM;
    float* PE = P2 + (size_t)LTOK * HDIM;
    float* AH1 = PE + (size_t)LTOK * HDIM;
    ushort* Ab = (ushort*)(AH1 + (size_t)LTOK * HDIM); // 4096*1536
    ushort* Wh = Ab + (size_t)LTOK * KA;               // 640*1536
    ushort* Wl = Wh + (size_t)NC * KA;
    ushort* W2h = Wl + (size_t)NC * KA;                // 160*160
    ushort* W2l = W2h + (size_t)K2 * K2;
    // total ~26.5 MB

    prep_kernel<<<(ITEMS_TOT + 255) / 256, 256, 0, stream>>>(
        embeds, states, aW1, sW1, sW2, Ab, Wh, Wl, W2h, W2l);
    k_proj<<<(LTOK / BM) * (NC / BN), 256, 0, stream>>>(
        Ab, Wh, Wl, ab1, P1, P2, PE, AH1);
    attn_tail<<<LTOK / 16, 256, 0, stream>>>(AH1, aW2, ab2, aW3, ab3, attns);
    span_kernel<<<(TOTAL_ROWS + RB2 - 1) / RB2, 256, 0, stream>>>(
        attns, P1, P2, PE, sb1, W2h, W2l, sb2, sW3, sb3, out);
}

// Round 5
// 224.238 us; speedup vs baseline: 3.0322x; 1.1965x over previous
//
#include <hip/hip_runtime.h>
#include <hip/hip_bf16.h>
#include <math.h>

#define LTOK 4096
#define EDIM 512
#define SDIM 1024
#define HDIM 150
#define PPAD 152           // padded row stride for P1/P2/PE (fp32, 16B-aligned rows)
#define MAXN 10
#define TOTAL_ROWS 40915   // sum_{n=1..10} (L - n + 1)
#define KA 1536            // padded K for token GEMM: 1024 states + 512 embeds
#define NC 640             // padded col count (600 real: P1|P2|AH1|PE)
#define K2 160             // padded K and N for 150x150 layers

typedef __attribute__((ext_vector_type(8))) short bfrag;   // 8 bf16 in 4 VGPRs
typedef __attribute__((ext_vector_type(4))) float ffrag;   // MFMA C/D

__device__ inline ushort f2bf(float f) {
    __hip_bfloat16 h = __float2bfloat16(f);
    return *(ushort*)&h;
}
__device__ inline float bf2f(ushort u) {
    __hip_bfloat16 h = *(__hip_bfloat16*)&u;
    return __bfloat162float(h);
}

#define ITEMS_A   (LTOK * (KA / 8))   // 786432  Ab
#define ITEMS_W   (NC * (KA / 8))     // 122880  Wh/Wl
#define ITEMS_W2  (K2 * (K2 / 8))     // 3200    W2h/W2l (sW2)
#define ITEMS_A2  (K2 * (K2 / 8))     // 3200    A2h/A2l (aW2)
#define ITEMS_Z   (LTOK * K2 / 8)     // 81920   zero AH1b (incl. k-pad)
#define ITEMS_TOT (ITEMS_A + ITEMS_W + ITEMS_W2 + ITEMS_A2 + ITEMS_Z)

// ---------------------------------------------------------------------------
// prep: bf16 conversions + transposes + hi/lo splits + AH1b zero-init.
// ---------------------------------------------------------------------------
__global__ __launch_bounds__(256) void prep_kernel(
    const float* __restrict__ embeds, const float* __restrict__ states,
    const float* __restrict__ aW1, const float* __restrict__ aW2,
    const float* __restrict__ sW1, const float* __restrict__ sW2,
    ushort* __restrict__ Ab, ushort* __restrict__ Wh, ushort* __restrict__ Wl,
    ushort* __restrict__ W2h, ushort* __restrict__ W2l,
    ushort* __restrict__ A2h, ushort* __restrict__ A2l,
    ushort* __restrict__ AH1b)
{
    int it = blockIdx.x * 256 + threadIdx.x;
    if (it < ITEMS_A) {
        const int r = it / (KA / 8), kc = it % (KA / 8);
        const int k0 = kc * 8;
        const float* src = (k0 < SDIM) ? (states + (size_t)r * SDIM + k0)
                                       : (embeds + (size_t)r * EDIM + (k0 - SDIM));
        const float4 v0 = *(const float4*)src;
        const float4 v1 = *(const float4*)(src + 4);
        ushort o[8] = {f2bf(v0.x), f2bf(v0.y), f2bf(v0.z), f2bf(v0.w),
                       f2bf(v1.x), f2bf(v1.y), f2bf(v1.z), f2bf(v1.w)};
        *(uint4*)(Ab + (size_t)r * KA + k0) = *(uint4*)o;
        return;
    }
    it -= ITEMS_A;
    if (it < ITEMS_W) {
        const int c = it / (KA / 8), kc = it % (KA / 8);
        const int k0 = kc * 8;
        const int g = (c < 600) ? (c / HDIM) : -1;
        const int cj = c % HDIM;
        ushort oh[8], ol[8];
        for (int j = 0; j < 8; ++j) {
            const int k = k0 + j;
            float wv = 0.f;
            if (g == 0 && k < SDIM) wv = sW1[(size_t)k * HDIM + cj];
            else if (g == 1 && k < SDIM) wv = sW1[(size_t)(SDIM + k) * HDIM + cj];
            else if (g == 2 && k < SDIM) wv = aW1[(size_t)k * HDIM + cj];
            else if (g == 3 && k >= SDIM) wv = sW1[(size_t)(SDIM + k) * HDIM + cj]; // rows 2048+(k-1024)
            const ushort hb = f2bf(wv);
            oh[j] = hb;
            ol[j] = f2bf(wv - bf2f(hb));
        }
        *(uint4*)(Wh + (size_t)c * KA + k0) = *(uint4*)oh;
        *(uint4*)(Wl + (size_t)c * KA + k0) = *(uint4*)ol;
        return;
    }
    it -= ITEMS_W;
    if (it < ITEMS_W2 + ITEMS_A2) {
        const bool is_a = (it >= ITEMS_W2);
        const int li = is_a ? (it - ITEMS_W2) : it;
        const float* src = is_a ? aW2 : sW2;
        ushort* dh = is_a ? A2h : W2h;
        ushort* dl = is_a ? A2l : W2l;
        const int c = li / (K2 / 8), kc = li % (K2 / 8);
        const int k0 = kc * 8;
        ushort oh[8], ol[8];
        for (int j = 0; j < 8; ++j) {
            const int k = k0 + j;
            float wv = (c < HDIM && k < HDIM) ? src[(size_t)k * HDIM + c] : 0.f;
            const ushort hb = f2bf(wv);
            oh[j] = hb;
            ol[j] = f2bf(wv - bf2f(hb));
        }
        *(uint4*)(dh + (size_t)c * K2 + k0) = *(uint4*)oh;
        *(uint4*)(dl + (size_t)c * K2 + k0) = *(uint4*)ol;
        return;
    }
    it -= ITEMS_W2 + ITEMS_A2;
    if (it < ITEMS_Z) {
        const uint4 z = {0u, 0u, 0u, 0u};
        *(uint4*)(AH1b + (size_t)it * 8) = z;
    }
}

// ---------------------------------------------------------------------------
// k_proj v2: C[4096 x 640] via mfma_f32_16x16x32_bf16.
// BM=64 x BN=64, grid 640 blocks, 4 waves as 2x2, wave-tile 32x32.
// A in LDS (double-buffered, pad-40 rows -> conflict-free b128), ONE barrier
// per k-iter, A prefetched 2 tiles ahead; B (hi/lo) streamed from L2.
// Epilogue: P1/P2/PE fp32 (PPAD rows); AH1 relu(+ab1) -> packed bf16 AH1b.
// ---------------------------------------------------------------------------
#define BM 64
#define BN 64
__global__ __launch_bounds__(256) void k_proj(
    const ushort* __restrict__ Ab, const ushort* __restrict__ Wh,
    const ushort* __restrict__ Wl, const float* __restrict__ ab1,
    float* __restrict__ P1, float* __restrict__ P2,
    float* __restrict__ PE, ushort* __restrict__ AH1b)
{
    const int bM = blockIdx.x & 63, bN = blockIdx.x >> 6;
    const int tid = threadIdx.x;
    const int w = tid >> 6, lane = tid & 63;
    const int quad = lane >> 4, l16 = lane & 15;
    const int wm = w & 1, wn = w >> 1;

    __shared__ __align__(16) ushort A_lds[2][64 * 40];   // pad 32->40 (bank-safe)

    ffrag acc[2][2];
#pragma unroll
    for (int t = 0; t < 2; ++t)
#pragma unroll
        for (int u = 0; u < 2; ++u) acc[t][u] = (ffrag){0.f, 0.f, 0.f, 0.f};

    const int rowg0 = bM * BM;
    const int srow = tid >> 2, skc = tid & 3;            // 64 rows x 4 k-chunks
    const ushort* agp = Ab + (size_t)(rowg0 + srow) * KA + skc * 8;
    const int lidx = srow * 40 + skc * 8;

    uint4 pv = *(const uint4*)agp;                       // tile 0
    *(uint4*)&A_lds[0][lidx] = pv;
    pv = *(const uint4*)(agp + 32);                      // tile 1

    const int colb = bN * BN + wn * 32;
    const int NKT = KA / 32;                             // 48

    for (int kt = 0; kt < NKT; ++kt) {
        __syncthreads();   // cur buffer written & prev readers of next buffer done
        if (kt + 1 < NKT) *(uint4*)&A_lds[(kt + 1) & 1][lidx] = pv;
        if (kt + 2 < NKT) pv = *(const uint4*)(agp + (size_t)(kt + 2) * 32);

        bfrag af[2];
        af[0] = *(const bfrag*)&A_lds[kt & 1][(wm * 32 + l16) * 40 + quad * 8];
        af[1] = *(const bfrag*)&A_lds[kt & 1][(wm * 32 + 16 + l16) * 40 + quad * 8];

        const int k0 = kt * 32;
#pragma unroll
        for (int u = 0; u < 2; ++u) {
            const int col = colb + u * 16 + l16;
            const bfrag bh = *(const bfrag*)(Wh + (size_t)col * KA + k0 + quad * 8);
            const bfrag bl = *(const bfrag*)(Wl + (size_t)col * KA + k0 + quad * 8);
#pragma unroll
            for (int t = 0; t < 2; ++t) {
                acc[t][u] = __builtin_amdgcn_mfma_f32_16x16x32_bf16(af[t], bh, acc[t][u], 0, 0, 0);
                acc[t][u] = __builtin_amdgcn_mfma_f32_16x16x32_bf16(af[t], bl, acc[t][u], 0, 0, 0);
            }
        }
    }

#pragma unroll
    for (int t = 0; t < 2; ++t)
#pragma unroll
        for (int u = 0; u < 2; ++u) {
            const int col = colb + u * 16 + l16;
#pragma unroll
            for (int r = 0; r < 4; ++r) {
                const int row = rowg0 + wm * 32 + t * 16 + quad * 4 + r;
                const float v = acc[t][u][r];
                if (col < 150)      P1[(size_t)row * PPAD + col] = v;
                else if (col < 300) P2[(size_t)row * PPAD + (col - 150)] = v;
                else if (col < 450) AH1b[(size_t)row * K2 + (col - 300)] =
                                        f2bf(fmaxf(v + ab1[col - 300], 0.f));
                else if (col < 600) PE[(size_t)row * PPAD + (col - 450)] = v;
            }
        }
}

// ---------------------------------------------------------------------------
// attn_tail v2 (MFMA): 64 tokens/block, grid 64. Per wave: 16 tokens.
// af from bf16 AH1b (global, 5 b128/lane); aW2 hi/lo streamed; relu*aW3
// epilogue; shfl-reduce over l16; attns out.
// ---------------------------------------------------------------------------
__global__ __launch_bounds__(256) void attn_tail(
    const ushort* __restrict__ AH1b, const ushort* __restrict__ A2h,
    const ushort* __restrict__ A2l, const float* __restrict__ ab2,
    const float* __restrict__ aW3, const float* __restrict__ ab3,
    float* __restrict__ attns)
{
    const int tok0 = blockIdx.x * 64;
    const int tid = threadIdx.x;
    const int w = tid >> 6, lane = tid & 63, quad = lane >> 4, l16 = lane & 15;

    bfrag af[5];
#pragma unroll
    for (int ks = 0; ks < 5; ++ks)
        af[ks] = *(const bfrag*)(AH1b + (size_t)(tok0 + w * 16 + l16) * K2 + ks * 32 + quad * 8);

    float part[4] = {0.f, 0.f, 0.f, 0.f};
    for (int ct = 0; ct < 10; ++ct) {
        ffrag acc = (ffrag){0.f, 0.f, 0.f, 0.f};
        const int col = ct * 16 + l16;
        const ushort* bh = A2h + (size_t)col * K2;
        const ushort* bl = A2l + (size_t)col * K2;
#pragma unroll
        for (int ks = 0; ks < 5; ++ks) {
            const bfrag fh = *(const bfrag*)(bh + ks * 32 + quad * 8);
            const bfrag fl = *(const bfrag*)(bl + ks * 32 + quad * 8);
            acc = __builtin_amdgcn_mfma_f32_16x16x32_bf16(af[ks], fh, acc, 0, 0, 0);
            acc = __builtin_amdgcn_mfma_f32_16x16x32_bf16(af[ks], fl, acc, 0, 0, 0);
        }
        const float s2 = (col < HDIM) ? ab2[col] : 0.f;
        const float s3 = (col < HDIM) ? aW3[col] : 0.f;
#pragma unroll
        for (int r = 0; r < 4; ++r) part[r] += fmaxf(acc[r] + s2, 0.f) * s3;
    }

#pragma unroll
    for (int off = 1; off < 16; off <<= 1) {
#pragma unroll
        for (int r = 0; r < 4; ++r) part[r] += __shfl_xor(part[r], off, 64);
    }
    if (l16 == 0) {
        const float b3 = ab3[0];
#pragma unroll
        for (int r = 0; r < 4; ++r)
            attns[tok0 + w * 16 + quad * 4 + r] = part[r] + b3;
    }
}

// ---------------------------------------------------------------------------
// span: 64 rows/block. softmax -> h1 (fp32 float4 build, ->bf16 LDS) ->
// MFMA layer-2 (A-frags in regs; W2 hi/lo from global) -> relu/sW3 ->
// shfl reduce -> out.
// ---------------------------------------------------------------------------
#define RB2 64
__global__ __launch_bounds__(256) void span_kernel(
    const float* __restrict__ attns, const float* __restrict__ P1,
    const float* __restrict__ P2, const float* __restrict__ PE,
    const float* __restrict__ sb1, const ushort* __restrict__ W2h,
    const ushort* __restrict__ W2l, const float* __restrict__ sb2,
    const float* __restrict__ sW3, const float* __restrict__ sb3,
    float* __restrict__ out)
{
    const int row0 = blockIdx.x * RB2;
    const int tid = threadIdx.x;
    const int w = tid >> 6, lane = tid & 63, quad = lane >> 4, l16 = lane & 15;

    __shared__ __align__(16) ushort h1b[RB2 * K2];
    __shared__ float wgt[RB2][MAXN];
    __shared__ int sm[RB2], sn[RB2];

    if (tid < RB2) {
        int row = row0 + tid;
        if (row >= TOTAL_ROWS) row = TOTAL_ROWS - 1;
        int idx = row, n = 1, m = 0;
        for (int nn = 1; nn <= MAXN; ++nn) {
            const int M = LTOK - nn + 1;
            if (idx < M) { n = nn; m = idx; break; }
            idx -= M;
        }
        sm[tid] = m; sn[tid] = n;
        float mx = -1e30f;
        for (int j = 0; j < n; ++j) mx = fmaxf(mx, attns[m + j]);
        float tp[MAXN]; float s = 0.f;
        for (int j = 0; j < n; ++j) { tp[j] = expf(attns[m + j] - mx); s += tp[j]; }
        const float inv = 1.f / s;
        for (int j = 0; j < n; ++j) wgt[tid][j] = tp[j] * inv;
    }
    __syncthreads();

    // phase 1: h1 fp32 (float4) -> bf16 LDS, k-pad zeroed
    for (int item = tid; item < RB2 * (K2 / 4); item += 256) {
        const int r = item / (K2 / 4), cq = item % (K2 / 4);
        const int c0 = cq * 4;
        const int m = sm[r], n = sn[r];
        float4 a = {0.f, 0.f, 0.f, 0.f};
        if (c0 < HDIM) {
            const float4 p1 = *(const float4*)(P1 + (size_t)m * PPAD + c0);
            const float4 p2 = *(const float4*)(P2 + (size_t)(m + n - 1) * PPAD + c0);
            a.x = p1.x + p2.x; a.y = p1.y + p2.y;
            a.z = p1.z + p2.z; a.w = p1.w + p2.w;
            for (int j = 0; j < n; ++j) {
                const float4 pe = *(const float4*)(PE + (size_t)(m + j) * PPAD + c0);
                const float wj = wgt[r][j];
                a.x = fmaf(wj, pe.x, a.x); a.y = fmaf(wj, pe.y, a.y);
                a.z = fmaf(wj, pe.z, a.z); a.w = fmaf(wj, pe.w, a.w);
            }
        }
        ushort o[4];
        o[0] = (c0 + 0 < HDIM) ? f2bf(fmaxf(a.x + sb1[c0 + 0], 0.f)) : (ushort)0;
        o[1] = (c0 + 1 < HDIM) ? f2bf(fmaxf(a.y + sb1[c0 + 1], 0.f)) : (ushort)0;
        o[2] = (c0 + 2 < HDIM) ? f2bf(fmaxf(a.z + sb1[c0 + 2], 0.f)) : (ushort)0;
        o[3] = (c0 + 3 < HDIM) ? f2bf(fmaxf(a.w + sb1[c0 + 3], 0.f)) : (ushort)0;
        *(uint2*)&h1b[r * K2 + c0] = *(uint2*)o;
    }
    __syncthreads();

    // phase 2: wave w -> rows w*16..+15, all 10 col-tiles
    bfrag af[5];
#pragma unroll
    for (int ks = 0; ks < 5; ++ks)
        af[ks] = *(const bfrag*)&h1b[(w * 16 + l16) * K2 + ks * 32 + quad * 8];

    float part[4] = {0.f, 0.f, 0.f, 0.f};
    for (int ct = 0; ct < 10; ++ct) {
        ffrag acc = (ffrag){0.f, 0.f, 0.f, 0.f};
        const int col = ct * 16 + l16;
        const ushort* bh = W2h + (size_t)col * K2;
        const ushort* bl = W2l + (size_t)col * K2;
#pragma unroll
        for (int ks = 0; ks < 5; ++ks) {
            const bfrag fh = *(const bfrag*)(bh + ks * 32 + quad * 8);
            const bfrag fl = *(const bfrag*)(bl + ks * 32 + quad * 8);
            acc = __builtin_amdgcn_mfma_f32_16x16x32_bf16(af[ks], fh, acc, 0, 0, 0);
            acc = __builtin_amdgcn_mfma_f32_16x16x32_bf16(af[ks], fl, acc, 0, 0, 0);
        }
        const float s2 = (col < HDIM) ? sb2[col] : 0.f;
        const float s3 = (col < HDIM) ? sW3[col] : 0.f;
#pragma unroll
        for (int r = 0; r < 4; ++r) part[r] += fmaxf(acc[r] + s2, 0.f) * s3;
    }

#pragma unroll
    for (int off = 1; off < 16; off <<= 1) {
#pragma unroll
        for (int r = 0; r < 4; ++r) part[r] += __shfl_xor(part[r], off, 64);
    }
    if (l16 == 0) {
        const float b3 = sb3[0];
#pragma unroll
        for (int r = 0; r < 4; ++r) {
            const int row = row0 + w * 16 + quad * 4 + r;
            if (row < TOTAL_ROWS) out[row] = part[r] + b3;
        }
    }
}

// ---------------------------------------------------------------------------
extern "C" void kernel_launch(void* const* d_in, const int* in_sizes, int n_in,
                              void* d_out, int out_size, void* d_ws, size_t ws_size,
                              hipStream_t stream) {
    const float* embeds = (const float*)d_in[0];
    const float* states = (const float*)d_in[1];
    const float* aW1 = (const float*)d_in[2];
    const float* ab1 = (const float*)d_in[3];
    const float* aW2 = (const float*)d_in[4];
    const float* ab2 = (const float*)d_in[5];
    const float* aW3 = (const float*)d_in[6];
    const float* ab3 = (const float*)d_in[7];
    const float* sW1 = (const float*)d_in[8];
    const float* sb1 = (const float*)d_in[9];
    const float* sW2 = (const float*)d_in[10];
    const float* sb2 = (const float*)d_in[11];
    const float* sW3 = (const float*)d_in[12];
    const float* sb3 = (const float*)d_in[13];
    float* out = (float*)d_out;

    // ws: fp32 attns | P1 | P2 | PE (PPAD rows), bf16 AH1b | Ab | Wh | Wl |
    //     W2h | W2l | A2h | A2l   (~25.5 MB)
    float* attns = (float*)d_ws;
    float* P1 = attns + LTOK;
    float* P2 = P1 + (size_t)LTOK * PPAD;
    float* PE = P2 + (size_t)LTOK * PPAD;
    ushort* AH1b = (ushort*)(PE + (size_t)LTOK * PPAD);  // LTOK*K2
    ushort* Ab  = AH1b + (size_t)LTOK * K2;              // LTOK*KA
    ushort* Wh  = Ab + (size_t)LTOK * KA;                // NC*KA
    ushort* Wl  = Wh + (size_t)NC * KA;
    ushort* W2h = Wl + (size_t)NC * KA;                  // K2*K2 each
    ushort* W2l = W2h + (size_t)K2 * K2;
    ushort* A2h = W2l + (size_t)K2 * K2;
    ushort* A2l = A2h + (size_t)K2 * K2;

    prep_kernel<<<(ITEMS_TOT + 255) / 256, 256, 0, stream>>>(
        embeds, states, aW1, aW2, sW1, sW2,
        Ab, Wh, Wl, W2h, W2l, A2h, A2l, AH1b);
    k_proj<<<(LTOK / BM) * (NC / BN), 256, 0, stream>>>(
        Ab, Wh, Wl, ab1, P1, P2, PE, AH1b);
    attn_tail<<<LTOK / 64, 256, 0, stream>>>(
        AH1b, A2h, A2l, ab2, aW3, ab3, attns);
    span_kernel<<<(TOTAL_ROWS + RB2 - 1) / RB2, 256, 0, stream>>>(
        attns, P1, P2, PE, sb1, W2h, W2l, sb2, sW3, sb3, out);
}